// Round 3
// baseline (901.560 us; speedup 1.0000x reference)
//
#include <hip/hip_runtime.h>
#include <stdint.h>

typedef __attribute__((ext_vector_type(8))) short short8;
typedef __attribute__((ext_vector_type(4))) float floatx4;
typedef __attribute__((ext_vector_type(4))) unsigned int uintx4;

__device__ __forceinline__ float bs2f(short s) {
  union { unsigned int u; float f; } cv;
  cv.u = ((unsigned int)(unsigned short)s) << 16;
  return cv.f;
}
__device__ __forceinline__ short f2bs(float x) {
  union { float f; unsigned int u; } cv; cv.f = x;
  unsigned int u = cv.u;
  u += 0x7fffu + ((u >> 16) & 1u);   // round-to-nearest-even
  return (short)(u >> 16);
}

#define BM 128
#define BN 128
#define BK 64

// C = A @ B^T + (optional resid).
// AFP32=1: A is fp32 [M,K], converted to bf16 during LDS staging.
// SCALEB=1: B tile (bf16 [N,K], shared across batches) is scaled by
//           gscale[batch*1024 + k] during staging; resid added in epilogue.
// OUTF32=1: C is fp32, else bf16.
template<int AFP32, int SCALEB, int OUTF32>
__global__ __launch_bounds__(256) void gemm_bt(
    const void* __restrict__ Av, const short* __restrict__ BT,
    void* __restrict__ Cv, const short* __restrict__ resid,
    const float* __restrict__ gscale, int M, int N, int K)
{
  __shared__ __align__(16) short As[BM * BK];
  __shared__ __align__(16) short Bs[BN * BK];
  const int tid  = threadIdx.x;
  const int wave = tid >> 6;
  const int lane = tid & 63;
  const int lm   = lane & 15;
  const int lq   = lane >> 4;
  const int m0 = blockIdx.y * BM;
  const int n0 = blockIdx.x * BN;
  const int wm = (wave & 1) * 64;
  const int wn = (wave >> 1) * 64;
  const int batch = m0 >> 11;        // rows are b*2048+s

  floatx4 acc[4][4];
#pragma unroll
  for (int r = 0; r < 4; ++r)
#pragma unroll
    for (int c = 0; c < 4; ++c) acc[r][c] = (floatx4)0.0f;

  for (int k0 = 0; k0 < K; k0 += BK) {
    __syncthreads();
#pragma unroll
    for (int it = 0; it < 4; ++it) {
      int chunk = it * 256 + tid;      // 0..1023, 8 elements each
      int r  = chunk >> 3;             // row 0..127
      int cc = (chunk & 7) * 8;        // col in elements
      // ---- A tile ----
      if (AFP32) {
        const float* A = (const float*)Av;
        const float* ap = &A[(size_t)(m0 + r) * K + k0 + cc];
        floatx4 f0 = *reinterpret_cast<const floatx4*>(ap);
        floatx4 f1 = *reinterpret_cast<const floatx4*>(ap + 4);
        short8 av;
#pragma unroll
        for (int e = 0; e < 4; ++e) { av[e] = f2bs(f0[e]); av[e + 4] = f2bs(f1[e]); }
        *reinterpret_cast<short8*>(&As[r * BK + cc]) = av;
      } else {
        const short* A = (const short*)Av;
        *reinterpret_cast<uintx4*>(&As[r * BK + cc]) =
            *reinterpret_cast<const uintx4*>(&A[(size_t)(m0 + r) * K + k0 + cc]);
      }
      // ---- B tile ----
      short8 bv = *reinterpret_cast<const short8*>(&BT[(size_t)(n0 + r) * K + k0 + cc]);
      if (SCALEB) {
        const float* g = gscale + batch * 1024 + k0 + cc;
        floatx4 g0 = *reinterpret_cast<const floatx4*>(g);
        floatx4 g1 = *reinterpret_cast<const floatx4*>(g + 4);
#pragma unroll
        for (int e = 0; e < 4; ++e) {
          bv[e]     = f2bs(bs2f(bv[e])     * g0[e]);
          bv[e + 4] = f2bs(bs2f(bv[e + 4]) * g1[e]);
        }
      }
      *reinterpret_cast<short8*>(&Bs[r * BK + cc]) = bv;
    }
    __syncthreads();
#pragma unroll
    for (int kk = 0; kk < BK; kk += 32) {
      short8 af[4], bfr[4];
#pragma unroll
      for (int r = 0; r < 4; ++r)
        af[r] = *reinterpret_cast<const short8*>(&As[(wm + r * 16 + lm) * BK + kk + lq * 8]);
#pragma unroll
      for (int c = 0; c < 4; ++c)
        bfr[c] = *reinterpret_cast<const short8*>(&Bs[(wn + c * 16 + lm) * BK + kk + lq * 8]);
#pragma unroll
      for (int r = 0; r < 4; ++r)
#pragma unroll
        for (int c = 0; c < 4; ++c)
          acc[r][c] = __builtin_amdgcn_mfma_f32_16x16x32_bf16(af[r], bfr[c], acc[r][c], 0, 0, 0);
    }
  }

#pragma unroll
  for (int r = 0; r < 4; ++r)
#pragma unroll
    for (int c = 0; c < 4; ++c) {
      int col = n0 + wn + c * 16 + lm;
#pragma unroll
      for (int reg = 0; reg < 4; ++reg) {
        int row = m0 + wm + r * 16 + lq * 4 + reg;   // C/D: col=lane&15, row=quad*4+reg
        size_t idx = (size_t)row * N + col;
        float v = acc[r][c][reg];
        if (SCALEB) v += bs2f(resid[idx]);
        if (OUTF32) ((float*)Cv)[idx] = v;
        else        ((short*)Cv)[idx] = f2bs(v);
      }
    }
}

// out[n][k] = bf16(in[k][n]) for 1024x1024 fp32 in
__global__ __launch_bounds__(256) void transpose_cvt(const float* __restrict__ in,
                                                     short* __restrict__ out) {
  __shared__ short tile[32][33];
  int bx = blockIdx.x * 32, by = blockIdx.y * 32;
  int tx = threadIdx.x & 31;
  int ty = threadIdx.x >> 5;   // 0..7
#pragma unroll
  for (int i = 0; i < 32; i += 8)
    tile[ty + i][tx] = f2bs(in[(size_t)(by + ty + i) * 1024 + bx + tx]);
  __syncthreads();
#pragma unroll
  for (int i = 0; i < 32; i += 8)
    out[(size_t)(bx + ty + i) * 1024 + by + tx] = tile[tx][ty + i];
}

// la[b][e][s] = 0.125 * sum_d Q[b,s,d] * Wa[d,e]   (Q bf16, Wa fp32 [1024,16])
__global__ __launch_bounds__(256) void q_logits(const short* __restrict__ Q,
                                                const float* __restrict__ Wa,
                                                float* __restrict__ out) {
  int wave = threadIdx.x >> 6, lane = threadIdx.x & 63;
  int sg = blockIdx.x * 4 + wave;           // 0..16383 = b*2048+s
  int b = sg >> 11, s = sg & 2047;
  const short* q = Q + (size_t)sg * 1024 + lane * 16;
  short8 q0 = *reinterpret_cast<const short8*>(q);
  short8 q1 = *reinterpret_cast<const short8*>(q + 8);
  float acc[16];
#pragma unroll
  for (int e = 0; e < 16; ++e) acc[e] = 0.f;
#pragma unroll
  for (int i = 0; i < 16; ++i) {
    float qv = bs2f(i < 8 ? q0[i] : q1[i - 8]);
    const float* w = Wa + (size_t)(lane * 16 + i) * 16;
    floatx4 w0 = *reinterpret_cast<const floatx4*>(w);
    floatx4 w1 = *reinterpret_cast<const floatx4*>(w + 4);
    floatx4 w2 = *reinterpret_cast<const floatx4*>(w + 8);
    floatx4 w3 = *reinterpret_cast<const floatx4*>(w + 12);
#pragma unroll
    for (int e = 0; e < 4; ++e) {
      acc[e]      += qv * w0[e];
      acc[e + 4]  += qv * w1[e];
      acc[e + 8]  += qv * w2[e];
      acc[e + 12] += qv * w3[e];
    }
  }
#pragma unroll
  for (int off = 32; off; off >>= 1)
#pragma unroll
    for (int e = 0; e < 16; ++e) acc[e] += __shfl_down(acc[e], off);
  if (lane == 0) {
#pragma unroll
    for (int e = 0; e < 16; ++e)
      out[(size_t)(b * 16 + e) * 2048 + s] = acc[e] * 0.125f;
  }
}

// lb[b][e][s'] with s'=h*128+t:
//   0.125 * sum_{u<16,j<64} KQ[b, t*16+u, h*64+j] * Wb[u*64+j, e]
__global__ __launch_bounds__(256) void b_logits(const short* __restrict__ KQ,
                                                const float* __restrict__ Wb,
                                                float* __restrict__ out) {
  int wave = threadIdx.x >> 6, lane = threadIdx.x & 63;
  int sg = blockIdx.x * 4 + wave;           // b*2048 + s'
  int b = sg >> 11, sp = sg & 2047;
  int h = sp >> 7, t = sp & 127;
  float acc[16];
#pragma unroll
  for (int e = 0; e < 16; ++e) acc[e] = 0.f;
  const short* kbase = KQ + ((size_t)b * 2048 + t * 16) * 1024 + h * 64 + lane;
#pragma unroll
  for (int u = 0; u < 16; ++u) {
    float kv = bs2f(kbase[(size_t)u * 1024]);
    const float* w = Wb + (size_t)(u * 64 + lane) * 16;
    floatx4 w0 = *reinterpret_cast<const floatx4*>(w);
    floatx4 w1 = *reinterpret_cast<const floatx4*>(w + 4);
    floatx4 w2 = *reinterpret_cast<const floatx4*>(w + 8);
    floatx4 w3 = *reinterpret_cast<const floatx4*>(w + 12);
#pragma unroll
    for (int e = 0; e < 4; ++e) {
      acc[e]      += kv * w0[e];
      acc[e + 4]  += kv * w1[e];
      acc[e + 8]  += kv * w2[e];
      acc[e + 12] += kv * w3[e];
    }
  }
#pragma unroll
  for (int off = 32; off; off >>= 1)
#pragma unroll
    for (int e = 0; e < 16; ++e) acc[e] += __shfl_down(acc[e], off);
  if (lane == 0) {
#pragma unroll
    for (int e = 0; e < 16; ++e)
      out[(size_t)(b * 16 + e) * 2048 + sp] = acc[e] * 0.125f;
  }
}

// per (b,h): softmax over 2048 logits (overwritten with probs), then
// out[bh*64+j] = sum_s p[s] * X[b, s, h*64+j]
__global__ __launch_bounds__(256) void softmax_pool(float* __restrict__ logits,
                                                    const short* __restrict__ X,
                                                    float* __restrict__ out) {
  __shared__ float red[256];
  int bh = blockIdx.x;
  int b = bh >> 4, h = bh & 15;
  int tid = threadIdx.x;
  float* l = logits + (size_t)bh * 2048;
  float v[8];
  float lm = -3.0e38f;
#pragma unroll
  for (int i = 0; i < 8; ++i) { v[i] = l[tid + i * 256]; lm = fmaxf(lm, v[i]); }
  red[tid] = lm; __syncthreads();
  for (int s2 = 128; s2 > 0; s2 >>= 1) {
    if (tid < s2) red[tid] = fmaxf(red[tid], red[tid + s2]);
    __syncthreads();
  }
  float m = red[0];
  __syncthreads();
  float ls = 0.f;
#pragma unroll
  for (int i = 0; i < 8; ++i) { v[i] = __expf(v[i] - m); ls += v[i]; }
  red[tid] = ls; __syncthreads();
  for (int s2 = 128; s2 > 0; s2 >>= 1) {
    if (tid < s2) red[tid] += red[tid + s2];
    __syncthreads();
  }
  float inv = 1.0f / red[0];
  __syncthreads();
#pragma unroll
  for (int i = 0; i < 8; ++i) l[tid + i * 256] = v[i] * inv;
  __syncthreads();
  int j = tid & 63, g = tid >> 6;
  const short* Xp = X + (size_t)b * 2048 * 1024 + h * 64 + j;
  float acc = 0.f;
  for (int s = g; s < 2048; s += 4)
    acc += l[s] * bs2f(Xp[(size_t)s * 1024]);
  red[tid] = acc; __syncthreads();
  if (g == 0) out[(size_t)bh * 64 + j] = red[j] + red[j + 64] + red[j + 128] + red[j + 192];
}

// Kb *= qg broadcast (in place): Kb[b,s,d] *= qg[b*1024+d]
__global__ __launch_bounds__(256) void scale_k(short* __restrict__ Kb,
                                               const float* __restrict__ qg) {
  size_t base = ((size_t)blockIdx.x * 256 + threadIdx.x) * 8;
  int b = (int)(base >> 21);          // 2048*1024 = 2^21
  int d = (int)(base & 1023);
  short8 v = *reinterpret_cast<short8*>(&Kb[base]);
  const float* q = qg + b * 1024 + d;
#pragma unroll
  for (int e = 0; e < 8; ++e) v[e] = f2bs(bs2f(v[e]) * q[e]);
  *reinterpret_cast<short8*>(&Kb[base]) = v;
}

extern "C" void kernel_launch(void* const* d_in, const int* in_sizes, int n_in,
                              void* d_out, int out_size, void* d_ws, size_t ws_size,
                              hipStream_t stream) {
  (void)in_sizes; (void)n_in; (void)out_size; (void)ws_size;
  const float* Qseq = (const float*)d_in[0];
  const float* Kseq = (const float*)d_in[1];
  // d_in[2] = V_seq, unused (faithful to reference)
  const float* WQ = (const float*)d_in[3];
  const float* WK = (const float*)d_in[4];
  const float* Wa = (const float*)d_in[5];
  const float* Wb = (const float*)d_in[6];
  const float* WP = (const float*)d_in[7];
  float* outp = (float*)d_out;   // reference returns float32

  char* ws = (char*)d_ws;
  const size_t MB = 1024 * 1024;
  short* Qb   = (short*)(ws + 0);           // 32 MB bf16 Q = Qseq@WQ
  short* Kb   = (short*)(ws + 32 * MB);     // 32 MB bf16 K, then KQ in place
  short* WQT  = (short*)(ws + 64 * MB);     // 2 MB bf16 WQ^T
  short* WKT  = (short*)(ws + 66 * MB);     // 2 MB bf16 WK^T
  short* WPTp = (short*)(ws + 68 * MB);     // 2 MB bf16 WP^T
  float* la   = (float*)(ws + 70 * MB);     // 1 MB alpha logits/probs
  float* lb   = (float*)(ws + 71 * MB);     // 1 MB beta logits/probs
  float* qg   = (float*)(ws + 72 * MB);     // 32 KB
  float* gv   = (float*)(ws + 72 * MB + 64 * 1024); // 32 KB

  dim3 tb(256);
  dim3 gT(32, 32);
  transpose_cvt<<<gT, tb, 0, stream>>>(WQ, WQT);
  transpose_cvt<<<gT, tb, 0, stream>>>(WK, WKT);
  transpose_cvt<<<gT, tb, 0, stream>>>(WP, WPTp);

  dim3 gG(1024 / BN, 16384 / BM);   // (8, 128)
  gemm_bt<1, 0, 0><<<gG, tb, 0, stream>>>(Qseq, WQT, Qb, nullptr, nullptr, 16384, 1024, 1024);
  gemm_bt<1, 0, 0><<<gG, tb, 0, stream>>>(Kseq, WKT, Kb, nullptr, nullptr, 16384, 1024, 1024);

  q_logits<<<4096, tb, 0, stream>>>(Qb, Wa, la);
  softmax_pool<<<128, tb, 0, stream>>>(la, Qb, qg);
  scale_k<<<8192, tb, 0, stream>>>(Kb, qg);
  b_logits<<<4096, tb, 0, stream>>>(Kb, Wb, lb);
  softmax_pool<<<128, tb, 0, stream>>>(lb, Kb, gv);
  gemm_bt<0, 1, 1><<<gG, tb, 0, stream>>>(Qb, WPTp, outp, Qb, gv, 16384, 1024, 1024);
}

// Round 4
// 611.293 us; speedup vs baseline: 1.4748x; 1.4748x over previous
//
#include <hip/hip_runtime.h>
#include <stdint.h>

typedef __attribute__((ext_vector_type(8))) short short8;
typedef __attribute__((ext_vector_type(4))) short sh4;
typedef __attribute__((ext_vector_type(4))) float floatx4;
typedef __attribute__((ext_vector_type(4))) unsigned int uintx4;

__device__ __forceinline__ float bs2f(short s) {
  union { unsigned int u; float f; } cv;
  cv.u = ((unsigned int)(unsigned short)s) << 16;
  return cv.f;
}
__device__ __forceinline__ short f2bs(float x) {
  union { float f; unsigned int u; } cv; cv.f = x;
  unsigned int u = cv.u;
  u += 0x7fffu + ((u >> 16) & 1u);   // round-to-nearest-even
  return (short)(u >> 16);
}
// pack two fp32 -> bf16x2 (round-half-up) in 3 VALU: two adds + v_perm
__device__ __forceinline__ unsigned int pack_bf16(float a, float b) {
  unsigned int ua = __float_as_uint(a) + 0x8000u;
  unsigned int ub = __float_as_uint(b) + 0x8000u;
  return __builtin_amdgcn_perm(ub, ua, 0x07060302u);  // [ub.hi16 : ua.hi16]
}
// async global->LDS, 16 bytes per lane (wave-uniform LDS base + lane*16)
__device__ __forceinline__ void async_copy16(const void* g, void* l) {
  __builtin_amdgcn_global_load_lds(
      (const __attribute__((address_space(1))) void*)g,
      (__attribute__((address_space(3))) void*)l, 16, 0, 0);
}

#define BM 128
#define BN 128
#define BK 64

// C = A @ B^T (+resid). A:[M,K], BT:[N,K].
// AFP32=1: A fp32, converted to bf16 via perm-pack during LDS staging.
// AFP32=0: A bf16, staged via global_load_lds (m97 style). B always async.
// RESID: add bf16 resid in epilogue. OUTF32: fp32 C, else bf16.
template<int AFP32, int RESID, int OUTF32>
__global__ __launch_bounds__(256) void gemm_bt(
    const void* __restrict__ Av, const short* __restrict__ BT,
    void* __restrict__ Cv, const short* __restrict__ resid,
    int M, int N, int K)
{
  __shared__ __align__(16) short As[BM * BK];
  __shared__ __align__(16) short Bs[BN * BK];
  const int tid  = threadIdx.x;
  const int wave = tid >> 6;
  const int lane = tid & 63;
  const int lm   = lane & 15;
  const int lq   = lane >> 4;
  const int m0 = blockIdx.y * BM;
  const int n0 = blockIdx.x * BN;
  const int wm = (wave & 1) * 64;
  const int wn = (wave >> 1) * 64;

  floatx4 acc[4][4];
#pragma unroll
  for (int r = 0; r < 4; ++r)
#pragma unroll
    for (int c = 0; c < 4; ++c) acc[r][c] = (floatx4)0.0f;

  for (int k0 = 0; k0 < K; k0 += BK) {
    __syncthreads();
    // B tile: async direct-to-LDS
#pragma unroll
    for (int it = 0; it < 4; ++it) {
      int chunk = it * 256 + tid;
      int r = chunk >> 3, cc = (chunk & 7) * 8;
      async_copy16(&BT[(size_t)(n0 + r) * K + k0 + cc], &Bs[r * BK + cc]);
    }
    if (AFP32) {
#pragma unroll
      for (int it = 0; it < 4; ++it) {
        int chunk = it * 256 + tid;
        int r = chunk >> 3, cc = (chunk & 7) * 8;
        const float* ap = &((const float*)Av)[(size_t)(m0 + r) * K + k0 + cc];
        floatx4 f0 = *reinterpret_cast<const floatx4*>(ap);
        floatx4 f1 = *reinterpret_cast<const floatx4*>(ap + 4);
        uintx4 av;
        av[0] = pack_bf16(f0[0], f0[1]); av[1] = pack_bf16(f0[2], f0[3]);
        av[2] = pack_bf16(f1[0], f1[1]); av[3] = pack_bf16(f1[2], f1[3]);
        *reinterpret_cast<uintx4*>(&As[r * BK + cc]) = av;
      }
    } else {
#pragma unroll
      for (int it = 0; it < 4; ++it) {
        int chunk = it * 256 + tid;
        int r = chunk >> 3, cc = (chunk & 7) * 8;
        async_copy16(&((const short*)Av)[(size_t)(m0 + r) * K + k0 + cc],
                     &As[r * BK + cc]);
      }
    }
    __syncthreads();
#pragma unroll
    for (int kk = 0; kk < BK; kk += 32) {
      short8 af[4], bfr[4];
#pragma unroll
      for (int r = 0; r < 4; ++r)
        af[r] = *reinterpret_cast<const short8*>(&As[(wm + r * 16 + lm) * BK + kk + lq * 8]);
#pragma unroll
      for (int c = 0; c < 4; ++c)
        bfr[c] = *reinterpret_cast<const short8*>(&Bs[(wn + c * 16 + lm) * BK + kk + lq * 8]);
#pragma unroll
      for (int r = 0; r < 4; ++r)
#pragma unroll
        for (int c = 0; c < 4; ++c)
          acc[r][c] = __builtin_amdgcn_mfma_f32_16x16x32_bf16(af[r], bfr[c], acc[r][c], 0, 0, 0);
    }
  }

#pragma unroll
  for (int r = 0; r < 4; ++r)
#pragma unroll
    for (int c = 0; c < 4; ++c) {
      int col = n0 + wn + c * 16 + lm;
#pragma unroll
      for (int reg = 0; reg < 4; ++reg) {
        int row = m0 + wm + r * 16 + lq * 4 + reg;   // C/D: col=lane&15, row=quad*4+reg
        size_t idx = (size_t)row * N + col;
        float v = acc[r][c][reg];
        if (RESID) v += bs2f(resid[idx]);
        if (OUTF32) ((float*)Cv)[idx] = v;
        else        ((short*)Cv)[idx] = f2bs(v);
      }
    }
}

// out[n][k] = bf16(in[k][n]) for 1024x1024 fp32 in
__global__ __launch_bounds__(256) void transpose_cvt(const float* __restrict__ in,
                                                     short* __restrict__ out) {
  __shared__ short tile[32][33];
  int bx = blockIdx.x * 32, by = blockIdx.y * 32;
  int tx = threadIdx.x & 31;
  int ty = threadIdx.x >> 5;
#pragma unroll
  for (int i = 0; i < 32; i += 8)
    tile[ty + i][tx] = f2bs(in[(size_t)(by + ty + i) * 1024 + bx + tx]);
  __syncthreads();
#pragma unroll
  for (int i = 0; i < 32; i += 8)
    out[(size_t)(bx + ty + i) * 1024 + by + tx] = tile[tx][ty + i];
}

// la[b][e][s] = 0.125 * sum_d Q[b,s,d] * Wa[d,e]   (Q bf16, Wa fp32 [1024,16])
__global__ __launch_bounds__(256) void q_logits(const short* __restrict__ Q,
                                                const float* __restrict__ Wa,
                                                float* __restrict__ out) {
  int wave = threadIdx.x >> 6, lane = threadIdx.x & 63;
  int sg = blockIdx.x * 4 + wave;           // b*2048+s
  int b = sg >> 11, s = sg & 2047;
  const short* q = Q + (size_t)sg * 1024 + lane * 16;
  short8 q0 = *reinterpret_cast<const short8*>(q);
  short8 q1 = *reinterpret_cast<const short8*>(q + 8);
  float acc[16];
#pragma unroll
  for (int e = 0; e < 16; ++e) acc[e] = 0.f;
#pragma unroll
  for (int i = 0; i < 16; ++i) {
    float qv = bs2f(i < 8 ? q0[i] : q1[i - 8]);
    const float* w = Wa + (size_t)(lane * 16 + i) * 16;
    floatx4 w0 = *reinterpret_cast<const floatx4*>(w);
    floatx4 w1 = *reinterpret_cast<const floatx4*>(w + 4);
    floatx4 w2 = *reinterpret_cast<const floatx4*>(w + 8);
    floatx4 w3 = *reinterpret_cast<const floatx4*>(w + 12);
#pragma unroll
    for (int e = 0; e < 4; ++e) {
      acc[e]      += qv * w0[e];
      acc[e + 4]  += qv * w1[e];
      acc[e + 8]  += qv * w2[e];
      acc[e + 12] += qv * w3[e];
    }
  }
#pragma unroll
  for (int off = 32; off; off >>= 1)
#pragma unroll
    for (int e = 0; e < 16; ++e) acc[e] += __shfl_down(acc[e], off);
  if (lane == 0) {
#pragma unroll
    for (int e = 0; e < 16; ++e)
      out[(size_t)(b * 16 + e) * 2048 + s] = acc[e] * 0.125f;
  }
}

// lb[b][e][s'], s'=h*128+t; QAK value folded as K*qg (fp32, no bf16 roundtrip):
//   0.125 * sum_{u,j} K[b,t*16+u,h*64+j]*qg[b,h*64+j] * Wb[u*64+j,e]
__global__ __launch_bounds__(256) void b_logits(const short* __restrict__ Kb,
                                                const float* __restrict__ Wb,
                                                const float* __restrict__ qg,
                                                float* __restrict__ out) {
  int wave = threadIdx.x >> 6, lane = threadIdx.x & 63;
  int sg = blockIdx.x * 4 + wave;           // b*2048 + s'
  int b = sg >> 11, sp = sg & 2047;
  int h = sp >> 7, t = sp & 127;
  float qgv = qg[b * 1024 + h * 64 + lane];
  float acc[16];
#pragma unroll
  for (int e = 0; e < 16; ++e) acc[e] = 0.f;
  const short* kbase = Kb + ((size_t)b * 2048 + t * 16) * 1024 + h * 64 + lane;
#pragma unroll
  for (int u = 0; u < 16; ++u) {
    float kv = bs2f(kbase[(size_t)u * 1024]) * qgv;
    const float* w = Wb + (size_t)(u * 64 + lane) * 16;
    floatx4 w0 = *reinterpret_cast<const floatx4*>(w);
    floatx4 w1 = *reinterpret_cast<const floatx4*>(w + 4);
    floatx4 w2 = *reinterpret_cast<const floatx4*>(w + 8);
    floatx4 w3 = *reinterpret_cast<const floatx4*>(w + 12);
#pragma unroll
    for (int e = 0; e < 4; ++e) {
      acc[e]      += kv * w0[e];
      acc[e + 4]  += kv * w1[e];
      acc[e + 8]  += kv * w2[e];
      acc[e + 12] += kv * w3[e];
    }
  }
#pragma unroll
  for (int off = 32; off; off >>= 1)
#pragma unroll
    for (int e = 0; e < 16; ++e) acc[e] += __shfl_down(acc[e], off);
  if (lane == 0) {
#pragma unroll
    for (int e = 0; e < 16; ++e)
      out[(size_t)(b * 16 + e) * 2048 + sp] = acc[e] * 0.125f;
  }
}

// in-place softmax over each 2048-row; grid = 128 (b,h) rows
__global__ __launch_bounds__(256) void softmax_rows(float* __restrict__ logits) {
  __shared__ float red[256];
  int tid = threadIdx.x;
  float* l = logits + (size_t)blockIdx.x * 2048;
  float v[8];
  float lm = -3.0e38f;
#pragma unroll
  for (int i = 0; i < 8; ++i) { v[i] = l[tid + i * 256]; lm = fmaxf(lm, v[i]); }
  red[tid] = lm; __syncthreads();
  for (int s2 = 128; s2 > 0; s2 >>= 1) {
    if (tid < s2) red[tid] = fmaxf(red[tid], red[tid + s2]);
    __syncthreads();
  }
  float m = red[0];
  __syncthreads();
  float ls = 0.f;
#pragma unroll
  for (int i = 0; i < 8; ++i) { v[i] = __expf(v[i] - m); ls += v[i]; }
  red[tid] = ls; __syncthreads();
  for (int s2 = 128; s2 > 0; s2 >>= 1) {
    if (tid < s2) red[tid] += red[tid + s2];
    __syncthreads();
  }
  float inv = 1.0f / red[0];
#pragma unroll
  for (int i = 0; i < 8; ++i) l[tid + i * 256] = v[i] * inv;
}

// partial weighted pooling: grid 512 (b=blk>>6, sc=blk&63), 32 s-rows each.
// part[blk][d] = sum_{s in chunk} probs[b, d>>6, s] * X[b,s,d]  (coalesced 8B/lane)
__global__ __launch_bounds__(256) void pool_partial(const float* __restrict__ probs,
                                                    const short* __restrict__ X,
                                                    float* __restrict__ part) {
  __shared__ float p[16][32];
  int blk = blockIdx.x, b = blk >> 6, sc = blk & 63, s0 = sc * 32;
  int tid = threadIdx.x;
  {
    int h = tid >> 4, ss = (tid & 15) * 2;
    const float* pr = probs + (size_t)(b * 16 + h) * 2048 + s0 + ss;
    p[h][ss] = pr[0]; p[h][ss + 1] = pr[1];
  }
  __syncthreads();
  int d = tid * 4, h = tid >> 4;
  float a0 = 0, a1 = 0, a2 = 0, a3 = 0;
  const short* Xp = X + ((size_t)b * 2048 + s0) * 1024 + d;
#pragma unroll 4
  for (int s = 0; s < 32; ++s) {
    sh4 x = *reinterpret_cast<const sh4*>(Xp + (size_t)s * 1024);
    float w = p[h][s];
    a0 += w * bs2f(x[0]); a1 += w * bs2f(x[1]);
    a2 += w * bs2f(x[2]); a3 += w * bs2f(x[3]);
  }
  float* o = part + (size_t)blk * 1024 + d;
  o[0] = a0; o[1] = a1; o[2] = a2; o[3] = a3;
}

// out[b*1024+d] = (SCALE ? g[b*1024+d] : 1) * sum_{sc<64} part[(b*64+sc)*1024+d]
template<int SCALE>
__global__ __launch_bounds__(256) void pool_reduce(const float* __restrict__ part,
                                                   const float* __restrict__ g,
                                                   float* __restrict__ out) {
  int b = blockIdx.x, d = threadIdx.x * 4;
  float a0 = 0, a1 = 0, a2 = 0, a3 = 0;
  for (int sc = 0; sc < 64; ++sc) {
    const float* pp = part + (size_t)(b * 64 + sc) * 1024 + d;
    a0 += pp[0]; a1 += pp[1]; a2 += pp[2]; a3 += pp[3];
  }
  if (SCALE) {
    const float* gp = g + b * 1024 + d;
    a0 *= gp[0]; a1 *= gp[1]; a2 *= gp[2]; a3 *= gp[3];
  }
  float* op = out + b * 1024 + d;
  op[0] = a0; op[1] = a1; op[2] = a2; op[3] = a3;
}

// QG[b,s,d] = bf16( Qb[b,s,d] * g[b*1024+d] )
__global__ __launch_bounds__(256) void scale_a(const short* __restrict__ Qb,
                                               const float* __restrict__ g,
                                               short* __restrict__ QG) {
  size_t base = ((size_t)blockIdx.x * 256 + threadIdx.x) * 8;
  int b = (int)(base >> 21), d = (int)(base & 1023);
  short8 v = *reinterpret_cast<const short8*>(&Qb[base]);
  const float* gp = g + b * 1024 + d;
#pragma unroll
  for (int e = 0; e < 8; ++e) v[e] = f2bs(bs2f(v[e]) * gp[e]);
  *reinterpret_cast<short8*>(&QG[base]) = v;
}

extern "C" void kernel_launch(void* const* d_in, const int* in_sizes, int n_in,
                              void* d_out, int out_size, void* d_ws, size_t ws_size,
                              hipStream_t stream) {
  (void)in_sizes; (void)n_in; (void)out_size; (void)ws_size;
  const float* Qseq = (const float*)d_in[0];
  const float* Kseq = (const float*)d_in[1];
  // d_in[2] = V_seq, unused (faithful to reference)
  const float* WQ = (const float*)d_in[3];
  const float* WK = (const float*)d_in[4];
  const float* Wa = (const float*)d_in[5];
  const float* Wb = (const float*)d_in[6];
  const float* WP = (const float*)d_in[7];
  float* outp = (float*)d_out;

  char* ws = (char*)d_ws;
  const size_t MB = 1024 * 1024;
  short* Qb   = (short*)(ws + 0);           // 32 MB bf16 Q
  short* Kb   = (short*)(ws + 32 * MB);     // 32 MB bf16 K; reused for QG after pool2
  short* WQT  = (short*)(ws + 64 * MB);     // 2 MB
  short* WKT  = (short*)(ws + 66 * MB);     // 2 MB
  short* WPT  = (short*)(ws + 68 * MB);     // 2 MB
  float* la   = (float*)(ws + 70 * MB);     // 1 MB
  float* lb   = (float*)(ws + 71 * MB);     // 1 MB
  float* qg   = (float*)(ws + 72 * MB);     // 32 KB
  float* gv   = (float*)(ws + 72 * MB + 64 * 1024); // 32 KB
  float* part = (float*)(ws + 73 * MB);     // 2 MB
  short* QG   = Kb;                         // Kb dead after pool2

  dim3 tb(256);
  dim3 gT(32, 32);
  transpose_cvt<<<gT, tb, 0, stream>>>(WQ, WQT);
  transpose_cvt<<<gT, tb, 0, stream>>>(WK, WKT);
  transpose_cvt<<<gT, tb, 0, stream>>>(WP, WPT);

  dim3 gG(1024 / BN, 16384 / BM);   // (8, 128)
  gemm_bt<1, 0, 0><<<gG, tb, 0, stream>>>(Qseq, WQT, Qb, nullptr, 16384, 1024, 1024);
  gemm_bt<1, 0, 0><<<gG, tb, 0, stream>>>(Kseq, WKT, Kb, nullptr, 16384, 1024, 1024);

  q_logits<<<4096, tb, 0, stream>>>(Qb, Wa, la);
  softmax_rows<<<128, tb, 0, stream>>>(la);
  pool_partial<<<512, tb, 0, stream>>>(la, Qb, part);
  pool_reduce<0><<<8, tb, 0, stream>>>(part, nullptr, qg);

  b_logits<<<4096, tb, 0, stream>>>(Kb, Wb, qg, lb);
  softmax_rows<<<128, tb, 0, stream>>>(lb);
  pool_partial<<<512, tb, 0, stream>>>(lb, Kb, part);
  pool_reduce<1><<<8, tb, 0, stream>>>(part, qg, gv);

  scale_a<<<8192, tb, 0, stream>>>(Qb, gv, QG);
  gemm_bt<0, 1, 1><<<gG, tb, 0, stream>>>(QG, WPT, outp, Qb, 16384, 1024, 1024);
}

// Round 5
// 458.064 us; speedup vs baseline: 1.9682x; 1.3345x over previous
//
#include <hip/hip_runtime.h>
#include <stdint.h>

typedef __attribute__((ext_vector_type(8))) short short8;
typedef __attribute__((ext_vector_type(4))) short sh4;
typedef __attribute__((ext_vector_type(4))) float floatx4;
typedef __attribute__((ext_vector_type(4))) unsigned int uintx4;

__device__ __forceinline__ float bs2f(short s) {
  union { unsigned int u; float f; } cv;
  cv.u = ((unsigned int)(unsigned short)s) << 16;
  return cv.f;
}
__device__ __forceinline__ short f2bs(float x) {
  union { float f; unsigned int u; } cv; cv.f = x;
  unsigned int u = cv.u;
  u += 0x7fffu + ((u >> 16) & 1u);   // round-to-nearest-even
  return (short)(u >> 16);
}
// pack two fp32 -> bf16x2 (round-half-up) in 3 VALU: two adds + v_perm
__device__ __forceinline__ unsigned int pack_bf16(float a, float b) {
  unsigned int ua = __float_as_uint(a) + 0x8000u;
  unsigned int ub = __float_as_uint(b) + 0x8000u;
  return __builtin_amdgcn_perm(ub, ua, 0x07060302u);  // [ub.hi16 : ua.hi16]
}
// async global->LDS, 16 bytes per lane (wave-uniform LDS base + lane*16)
__device__ __forceinline__ void async_copy16(const void* g, void* l) {
  __builtin_amdgcn_global_load_lds(
      (const __attribute__((address_space(1))) void*)g,
      (__attribute__((address_space(3))) void*)l, 16, 0, 0);
}

#define BM 128
#define BN 128
#define BK 64

// C = A @ B^T (+resid). A:[M,K], BT:[N,K].
// AFP32=1: A fp32, converted to bf16 via perm-pack during LDS staging.
// AFP32=0: A bf16, staged via global_load_lds (m97 style). B always async.
// RESID: add bf16 resid in epilogue. OUTF32: fp32 C, else bf16.
template<int AFP32, int RESID, int OUTF32>
__global__ __launch_bounds__(256) void gemm_bt(
    const void* __restrict__ Av, const short* __restrict__ BT,
    void* __restrict__ Cv, const short* __restrict__ resid,
    int M, int N, int K)
{
  __shared__ __align__(16) short As[BM * BK];
  __shared__ __align__(16) short Bs[BN * BK];
  const int tid  = threadIdx.x;
  const int wave = tid >> 6;
  const int lane = tid & 63;
  const int lm   = lane & 15;
  const int lq   = lane >> 4;
  const int m0 = blockIdx.y * BM;
  const int n0 = blockIdx.x * BN;
  const int wm = (wave & 1) * 64;
  const int wn = (wave >> 1) * 64;

  floatx4 acc[4][4];
#pragma unroll
  for (int r = 0; r < 4; ++r)
#pragma unroll
    for (int c = 0; c < 4; ++c) acc[r][c] = (floatx4)0.0f;

  for (int k0 = 0; k0 < K; k0 += BK) {
    __syncthreads();
    // B tile: async direct-to-LDS
#pragma unroll
    for (int it = 0; it < 4; ++it) {
      int chunk = it * 256 + tid;
      int r = chunk >> 3, cc = (chunk & 7) * 8;
      async_copy16(&BT[(size_t)(n0 + r) * K + k0 + cc], &Bs[r * BK + cc]);
    }
    if (AFP32) {
#pragma unroll
      for (int it = 0; it < 4; ++it) {
        int chunk = it * 256 + tid;
        int r = chunk >> 3, cc = (chunk & 7) * 8;
        const float* ap = &((const float*)Av)[(size_t)(m0 + r) * K + k0 + cc];
        floatx4 f0 = *reinterpret_cast<const floatx4*>(ap);
        floatx4 f1 = *reinterpret_cast<const floatx4*>(ap + 4);
        uintx4 av;
        av[0] = pack_bf16(f0[0], f0[1]); av[1] = pack_bf16(f0[2], f0[3]);
        av[2] = pack_bf16(f1[0], f1[1]); av[3] = pack_bf16(f1[2], f1[3]);
        *reinterpret_cast<uintx4*>(&As[r * BK + cc]) = av;
      }
    } else {
#pragma unroll
      for (int it = 0; it < 4; ++it) {
        int chunk = it * 256 + tid;
        int r = chunk >> 3, cc = (chunk & 7) * 8;
        async_copy16(&((const short*)Av)[(size_t)(m0 + r) * K + k0 + cc],
                     &As[r * BK + cc]);
      }
    }
    __syncthreads();
#pragma unroll
    for (int kk = 0; kk < BK; kk += 32) {
      short8 af[4], bfr[4];
#pragma unroll
      for (int r = 0; r < 4; ++r)
        af[r] = *reinterpret_cast<const short8*>(&As[(wm + r * 16 + lm) * BK + kk + lq * 8]);
#pragma unroll
      for (int c = 0; c < 4; ++c)
        bfr[c] = *reinterpret_cast<const short8*>(&Bs[(wn + c * 16 + lm) * BK + kk + lq * 8]);
#pragma unroll
      for (int r = 0; r < 4; ++r)
#pragma unroll
        for (int c = 0; c < 4; ++c)
          acc[r][c] = __builtin_amdgcn_mfma_f32_16x16x32_bf16(af[r], bfr[c], acc[r][c], 0, 0, 0);
    }
  }

#pragma unroll
  for (int r = 0; r < 4; ++r)
#pragma unroll
    for (int c = 0; c < 4; ++c) {
      int col = n0 + wn + c * 16 + lm;
#pragma unroll
      for (int reg = 0; reg < 4; ++reg) {
        int row = m0 + wm + r * 16 + lq * 4 + reg;   // C/D: col=lane&15, row=quad*4+reg
        size_t idx = (size_t)row * N + col;
        float v = acc[r][c][reg];
        if (RESID) v += bs2f(resid[idx]);
        if (OUTF32) ((float*)Cv)[idx] = v;
        else        ((short*)Cv)[idx] = f2bs(v);
      }
    }
}

// out[n][k] = bf16(in[k][n]) for 1024x1024 fp32; blockIdx.z selects matrix
__global__ __launch_bounds__(256) void transpose_cvt3(
    const float* __restrict__ i0, const float* __restrict__ i1,
    const float* __restrict__ i2, short* __restrict__ o0,
    short* __restrict__ o1, short* __restrict__ o2) {
  const float* in = blockIdx.z == 0 ? i0 : (blockIdx.z == 1 ? i1 : i2);
  short* out = blockIdx.z == 0 ? o0 : (blockIdx.z == 1 ? o1 : o2);
  __shared__ short tile[32][33];
  int bx = blockIdx.x * 32, by = blockIdx.y * 32;
  int tx = threadIdx.x & 31;
  int ty = threadIdx.x >> 5;
#pragma unroll
  for (int i = 0; i < 32; i += 8)
    tile[ty + i][tx] = f2bs(in[(size_t)(by + ty + i) * 1024 + bx + tx]);
  __syncthreads();
#pragma unroll
  for (int i = 0; i < 32; i += 8)
    out[(size_t)(bx + ty + i) * 1024 + by + tx] = tile[tx][ty + i];
}

// WaB[e][k] = bf16(Wa[k][e]), same for Wb. grid 128 x 256.
__global__ __launch_bounds__(256) void w_transpose(const float* __restrict__ Wa,
                                                   const float* __restrict__ Wb,
                                                   short* __restrict__ WaB,
                                                   short* __restrict__ WbB) {
  int idx = blockIdx.x * 256 + threadIdx.x;   // 0..32767
  const float* src = idx < 16384 ? Wa : Wb;
  short* dst = idx < 16384 ? WaB : WbB;
  int i = idx & 16383;
  int e = i >> 10, k = i & 1023;
  dst[i] = f2bs(src[k * 16 + e]);
}

// Skinny MFMA GEMM: out[(b*16+e)*2048 + s] = 0.125 * sum_k A[row,k] * W[k,e]
// SCRAMBLE=0: A row = blk*16+m directly from X (Qb).
// SCRAMBLE=1: row sp=h*128+t reads X=Kb[b, t*16+u, h*64+j] * qg[b,h*64+j]
//             (the Fastformer reshape scramble; j-chunks stay contiguous).
// WB is W^T as bf16 [16][1024]. One wave per 16-row strip; grid 1024.
template<int SCRAMBLE>
__global__ __launch_bounds__(64) void skinny_logits(
    const short* __restrict__ X, const short* __restrict__ WB,
    const float* __restrict__ qg, float* __restrict__ out)
{
  const int lane = threadIdx.x;
  const int lm = lane & 15, lq = lane >> 4;
  const int blk = blockIdx.x;           // 0..1023
  const int b = blk >> 7;
  const int s0 = (blk & 127) * 16;      // row offset within batch
  floatx4 acc = (floatx4)0.0f;
  const short* b0 = WB + lm * 1024 + lq * 8;

  if (!SCRAMBLE) {
    const short* a0 = X + ((size_t)(b * 2048 + s0 + lm)) * 1024 + lq * 8;
#pragma unroll 16
    for (int c = 0; c < 32; ++c) {
      short8 a  = *reinterpret_cast<const short8*>(a0 + c * 32);
      short8 bf = *reinterpret_cast<const short8*>(b0 + c * 32);
      acc = __builtin_amdgcn_mfma_f32_16x16x32_bf16(a, bf, acc, 0, 0, 0);
    }
  } else {
    const int h = s0 >> 7, t0 = s0 & 127;
    const float* qgp = qg + b * 1024 + h * 64;
    const short* xb = X + ((size_t)(b * 2048 + (t0 + lm) * 16)) * 1024 + h * 64;
#pragma unroll 16
    for (int c = 0; c < 32; ++c) {
      int dp = c * 32 + lq * 8;         // k index within 1024
      int u = dp >> 6, j0 = dp & 63;    // 8-aligned, never crosses u
      short8 a = *reinterpret_cast<const short8*>(xb + (size_t)u * 1024 + j0);
      floatx4 g0 = *reinterpret_cast<const floatx4*>(qgp + j0);
      floatx4 g1 = *reinterpret_cast<const floatx4*>(qgp + j0 + 4);
      uintx4 av;
      av[0] = pack_bf16(bs2f(a[0]) * g0[0], bs2f(a[1]) * g0[1]);
      av[1] = pack_bf16(bs2f(a[2]) * g0[2], bs2f(a[3]) * g0[3]);
      av[2] = pack_bf16(bs2f(a[4]) * g1[0], bs2f(a[5]) * g1[1]);
      av[3] = pack_bf16(bs2f(a[6]) * g1[2], bs2f(a[7]) * g1[3]);
      short8 as = __builtin_bit_cast(short8, av);
      short8 bf = *reinterpret_cast<const short8*>(b0 + c * 32);
      acc = __builtin_amdgcn_mfma_f32_16x16x32_bf16(as, bf, acc, 0, 0, 0);
    }
  }
  // D: col(e)=lane&15, row=lq*4+reg; rows are consecutive s -> float4 store
  float* o = out + ((size_t)(b * 16 + lm)) * 2048 + s0 + lq * 4;
  floatx4 r;
#pragma unroll
  for (int i = 0; i < 4; ++i) r[i] = acc[i] * 0.125f;
  *reinterpret_cast<floatx4*>(o) = r;
}

// in-place softmax over each 2048-row; grid = 128 (b,h) rows
__global__ __launch_bounds__(256) void softmax_rows(float* __restrict__ logits) {
  __shared__ float red[256];
  int tid = threadIdx.x;
  float* l = logits + (size_t)blockIdx.x * 2048;
  float v[8];
  float lm = -3.0e38f;
#pragma unroll
  for (int i = 0; i < 8; ++i) { v[i] = l[tid + i * 256]; lm = fmaxf(lm, v[i]); }
  red[tid] = lm; __syncthreads();
  for (int s2 = 128; s2 > 0; s2 >>= 1) {
    if (tid < s2) red[tid] = fmaxf(red[tid], red[tid + s2]);
    __syncthreads();
  }
  float m = red[0];
  __syncthreads();
  float ls = 0.f;
#pragma unroll
  for (int i = 0; i < 8; ++i) { v[i] = __expf(v[i] - m); ls += v[i]; }
  red[tid] = ls; __syncthreads();
  for (int s2 = 128; s2 > 0; s2 >>= 1) {
    if (tid < s2) red[tid] += red[tid + s2];
    __syncthreads();
  }
  float inv = 1.0f / red[0];
#pragma unroll
  for (int i = 0; i < 8; ++i) l[tid + i * 256] = v[i] * inv;
}

// partial weighted pooling: grid 512 (b=blk>>6, sc=blk&63), 32 s-rows each.
// part[blk][d] = sum_{s in chunk} probs[b, d>>6, s] * X[b,s,d]  (coalesced 8B/lane)
__global__ __launch_bounds__(256) void pool_partial(const float* __restrict__ probs,
                                                    const short* __restrict__ X,
                                                    float* __restrict__ part) {
  __shared__ float p[16][32];
  int blk = blockIdx.x, b = blk >> 6, sc = blk & 63, s0 = sc * 32;
  int tid = threadIdx.x;
  {
    int h = tid >> 4, ss = (tid & 15) * 2;
    const float* pr = probs + (size_t)(b * 16 + h) * 2048 + s0 + ss;
    p[h][ss] = pr[0]; p[h][ss + 1] = pr[1];
  }
  __syncthreads();
  int d = tid * 4, h = tid >> 4;
  float a0 = 0, a1 = 0, a2 = 0, a3 = 0;
  const short* Xp = X + ((size_t)b * 2048 + s0) * 1024 + d;
#pragma unroll 4
  for (int s = 0; s < 32; ++s) {
    sh4 x = *reinterpret_cast<const sh4*>(Xp + (size_t)s * 1024);
    float w = p[h][s];
    a0 += w * bs2f(x[0]); a1 += w * bs2f(x[1]);
    a2 += w * bs2f(x[2]); a3 += w * bs2f(x[3]);
  }
  float* o = part + (size_t)blk * 1024 + d;
  o[0] = a0; o[1] = a1; o[2] = a2; o[3] = a3;
}

// out[b*1024+d] = (SCALE ? g[b*1024+d] : 1) * sum_{sc<64} part[(b*64+sc)*1024+d]
template<int SCALE>
__global__ __launch_bounds__(256) void pool_reduce(const float* __restrict__ part,
                                                   const float* __restrict__ g,
                                                   float* __restrict__ out) {
  int b = blockIdx.x, d = threadIdx.x * 4;
  float a0 = 0, a1 = 0, a2 = 0, a3 = 0;
  for (int sc = 0; sc < 64; ++sc) {
    const float* pp = part + (size_t)(b * 64 + sc) * 1024 + d;
    a0 += pp[0]; a1 += pp[1]; a2 += pp[2]; a3 += pp[3];
  }
  if (SCALE) {
    const float* gp = g + b * 1024 + d;
    a0 *= gp[0]; a1 *= gp[1]; a2 *= gp[2]; a3 *= gp[3];
  }
  float* op = out + b * 1024 + d;
  op[0] = a0; op[1] = a1; op[2] = a2; op[3] = a3;
}

// QG[b,s,d] = bf16( Qb[b,s,d] * g[b*1024+d] )
__global__ __launch_bounds__(256) void scale_a(const short* __restrict__ Qb,
                                               const float* __restrict__ g,
                                               short* __restrict__ QG) {
  size_t base = ((size_t)blockIdx.x * 256 + threadIdx.x) * 8;
  int b = (int)(base >> 21), d = (int)(base & 1023);
  short8 v = *reinterpret_cast<const short8*>(&Qb[base]);
  const float* gp = g + b * 1024 + d;
#pragma unroll
  for (int e = 0; e < 8; ++e) v[e] = f2bs(bs2f(v[e]) * gp[e]);
  *reinterpret_cast<short8*>(&QG[base]) = v;
}

extern "C" void kernel_launch(void* const* d_in, const int* in_sizes, int n_in,
                              void* d_out, int out_size, void* d_ws, size_t ws_size,
                              hipStream_t stream) {
  (void)in_sizes; (void)n_in; (void)out_size; (void)ws_size;
  const float* Qseq = (const float*)d_in[0];
  const float* Kseq = (const float*)d_in[1];
  // d_in[2] = V_seq, unused (faithful to reference)
  const float* WQ = (const float*)d_in[3];
  const float* WK = (const float*)d_in[4];
  const float* Wa = (const float*)d_in[5];
  const float* Wb = (const float*)d_in[6];
  const float* WP = (const float*)d_in[7];
  float* outp = (float*)d_out;

  char* ws = (char*)d_ws;
  const size_t MB = 1024 * 1024;
  short* Qb   = (short*)(ws + 0);           // 32 MB bf16 Q
  short* Kb   = (short*)(ws + 32 * MB);     // 32 MB bf16 K; reused for QG after pool2
  short* WQT  = (short*)(ws + 64 * MB);     // 2 MB
  short* WKT  = (short*)(ws + 66 * MB);     // 2 MB
  short* WPT  = (short*)(ws + 68 * MB);     // 2 MB
  float* la   = (float*)(ws + 70 * MB);     // 1 MB
  float* lb   = (float*)(ws + 71 * MB);     // 1 MB
  float* qg   = (float*)(ws + 72 * MB);     // 32 KB
  float* gv   = (float*)(ws + 72 * MB + 64 * 1024); // 32 KB
  short* WaB  = (short*)(ws + 72 * MB + 128 * 1024); // 32 KB bf16 Wa^T
  short* WbB  = (short*)(ws + 72 * MB + 192 * 1024); // 32 KB bf16 Wb^T
  float* part = (float*)(ws + 73 * MB);     // 2 MB
  short* QG   = Kb;                         // Kb dead after pool2

  dim3 tb(256);
  transpose_cvt3<<<dim3(32, 32, 3), tb, 0, stream>>>(WQ, WK, WP, WQT, WKT, WPT);
  w_transpose<<<128, tb, 0, stream>>>(Wa, Wb, WaB, WbB);

  dim3 gG(1024 / BN, 16384 / BM);   // (8, 128)
  gemm_bt<1, 0, 0><<<gG, tb, 0, stream>>>(Qseq, WQT, Qb, nullptr, 16384, 1024, 1024);
  gemm_bt<1, 0, 0><<<gG, tb, 0, stream>>>(Kseq, WKT, Kb, nullptr, 16384, 1024, 1024);

  skinny_logits<0><<<1024, 64, 0, stream>>>(Qb, WaB, nullptr, la);
  softmax_rows<<<128, tb, 0, stream>>>(la);
  pool_partial<<<512, tb, 0, stream>>>(la, Qb, part);
  pool_reduce<0><<<8, tb, 0, stream>>>(part, nullptr, qg);

  skinny_logits<1><<<1024, 64, 0, stream>>>(Kb, WbB, qg, lb);
  softmax_rows<<<128, tb, 0, stream>>>(lb);
  pool_partial<<<512, tb, 0, stream>>>(lb, Kb, part);
  pool_reduce<1><<<8, tb, 0, stream>>>(part, qg, gv);

  scale_a<<<8192, tb, 0, stream>>>(Qb, gv, QG);
  gemm_bt<0, 1, 1><<<gG, tb, 0, stream>>>(QG, WPT, outp, Qb, 16384, 1024, 1024);
}